// Round 14
// baseline (252.810 us; speedup 1.0000x reference)
//
#include <hip/hip_runtime.h>

// MultiHeadAttention: B=4, S=2048, D=1024, H=16, DK=64
// R14: 4 dispatches (was 6) — prep (cvtx+wtrans merged), proj (projA+projB
// merged, grid 8x64, whole-block branch), flash attention, output GEMM.
// Kernel internals are byte-identical to the R10/R13-verified versions;
// only block-id plumbing changed. Attacks the ~70us inter-dispatch gap
// budget (per-kernel counters were deterministic across R10/R12/R13).

typedef __attribute__((ext_vector_type(8))) short short8;
typedef __attribute__((ext_vector_type(4))) float floatx4;
typedef __attribute__((ext_vector_type(4))) unsigned short ushort4v;

#define SCLF (0.125f * 1.44269504f)

__device__ __forceinline__ unsigned short f2bf(float f) {
    unsigned int u = __float_as_uint(f);
    unsigned int r = (u + 0x7fffu + ((u >> 16) & 1u)) >> 16;
    return (unsigned short)r;
}

__device__ __forceinline__ unsigned int pk2bf(float lo, float hi) {
    return __builtin_amdgcn_perm(__float_as_uint(hi), __float_as_uint(lo), 0x07060302u);
}

__device__ __forceinline__ void gll16(const unsigned short* g, unsigned short* l) {
    __builtin_amdgcn_global_load_lds(
        (const __attribute__((address_space(1))) unsigned int*)g,
        (__attribute__((address_space(3))) unsigned int*)l, 16, 0, 0);
}

// ---------------- prep: cvtx (blocks 0..8191) + wtrans (blocks 8192..12287) ----------------
__global__ void prep_kernel(const float* __restrict__ x, unsigned short* __restrict__ xb,
                            const float* __restrict__ wq, const float* __restrict__ wk,
                            const float* __restrict__ wv, const float* __restrict__ wo,
                            unsigned short* __restrict__ wtbase) {
    __shared__ float t[32][33];
    int blk = blockIdx.x;
    if (blk < 8192) {
        int i = (blk * 256 + threadIdx.x) * 4;
        float4 v = *(const float4*)&x[i];
        ushort4v o;
        o.x = f2bf(v.x); o.y = f2bf(v.y); o.z = f2bf(v.z); o.w = f2bf(v.w);
        *(ushort4v*)&xb[i] = o;
    } else {
        int bb = blk - 8192;
        int z = bb >> 10;            // 1024 blocks per weight
        int rem = bb & 1023;
        int by = rem >> 5, bx = rem & 31;
        const float* w = (z == 0) ? wq : (z == 1) ? wk : (z == 2) ? wv : wo;
        unsigned short* wt = wtbase + ((long)z << 20);
        int kb = by * 32, nb = bx * 32;
        int col = threadIdx.x & 31, rw = threadIdx.x >> 5;
#pragma unroll
        for (int i = 0; i < 4; i++) {
            int row = rw + i * 8;
            t[row][col] = w[(kb + row) * 1024 + nb + col];
        }
        __syncthreads();
#pragma unroll
        for (int i = 0; i < 4; i++) {
            int row = rw + i * 8;
            wt[(nb + row) * 1024 + kb + col] = f2bf(t[col][row]);
        }
    }
}

__device__ __forceinline__ short8 ldsr(const unsigned short* p) { return *(const short8*)p; }

// ================= CORE 1: 256x256, BK=64, 8 waves, 4-phase (verified) =================
#define ASQ (256 * 64)
#define BUFSQ (2 * ASQ)

template <bool SW>
__device__ __forceinline__ void gemm_core256sq(const unsigned short* __restrict__ A,
                                               const unsigned short* __restrict__ Bt,
                                               unsigned short* lds,
                                               int m0, int n0, floatx4 (&acc)[8][4]) {
    const int K = 1024, NT = 16;
    int tid = threadIdx.x;
    int lane = tid & 63, wave = tid >> 6;   // 8 waves: 2 (M) x 4 (N)
    int wm = wave >> 2, wn = wave & 3;      // per-wave C: 128x64
    int quad = lane >> 4, l15 = lane & 15, l7 = l15 & 7;
    int rsub = lane >> 3;
    int gl = (lane & 7) ^ rsub;

    floatx4 zero4 = {0.f, 0.f, 0.f, 0.f};
#pragma unroll
    for (int i = 0; i < 8; i++)
#pragma unroll
        for (int j = 0; j < 4; j++) acc[i][j] = zero4;

    auto stageA = [&](int kt, int half) {
        const unsigned short* Ag = A + (long)m0 * K + kt * 64;
        unsigned short* as = lds + (kt & 1) * BUFSQ;
#pragma unroll
        for (int p = 0; p < 2; p++) {
            int chunk = half * 16 + wave * 2 + p;
            gll16(&Ag[(chunk * 8 + rsub) * K + gl * 8], &as[chunk * 512 + lane * 8]);
        }
    };
    auto stageB = [&](int kt, int half) {
        const unsigned short* Bg = Bt + (long)n0 * K + kt * 64;
        unsigned short* bs = lds + (kt & 1) * BUFSQ + ASQ;
#pragma unroll
        for (int p = 0; p < 2; p++) {
            int chunk = half * 16 + wave * 2 + p;
            gll16(&Bg[(chunk * 8 + rsub) * K + gl * 8], &bs[chunk * 512 + lane * 8]);
        }
    };

    stageA(0, 0); stageA(0, 1); stageB(0, 0); stageB(0, 1);
    stageB(1, 0); stageA(1, 0); stageB(1, 1);
    asm volatile("s_waitcnt vmcnt(6)" ::: "memory");
    __builtin_amdgcn_s_barrier();
    asm volatile("" ::: "memory");

    short8 af[4][2], b0[2][2], b1[2][2];

    for (int kt = 0; kt < NT; kt++) {
        const unsigned short* as = lds + (kt & 1) * BUFSQ;
        const unsigned short* bs = as + ASQ;

        // ph0: read A-low + B0; stage A(kt+1,h1) (other buffer); MFMA (Alo,B0)
#pragma unroll
        for (int i = 0; i < 4; i++) {
            int r = wm * 128 + i * 16 + l15;
            af[i][0] = ldsr(&as[r * 64 + ((quad ^ l7) * 8)]);
            af[i][1] = ldsr(&as[r * 64 + (((4 + quad) ^ l7) * 8)]);
        }
#pragma unroll
        for (int j = 0; j < 2; j++) {
            int r = wn * 64 + j * 16 + l15;
            b0[j][0] = ldsr(&bs[r * 64 + ((quad ^ l7) * 8)]);
            b0[j][1] = ldsr(&bs[r * 64 + (((4 + quad) ^ l7) * 8)]);
        }
        if (kt + 1 < NT) stageA(kt + 1, 1);
        asm volatile("" ::: "memory");
        __builtin_amdgcn_s_barrier();
        asm volatile("s_waitcnt lgkmcnt(0)" ::: "memory");
        __builtin_amdgcn_sched_barrier(0);
        __builtin_amdgcn_s_setprio(1);
#pragma unroll
        for (int i = 0; i < 4; i++)
#pragma unroll
            for (int j = 0; j < 2; j++)
#pragma unroll
                for (int kk = 0; kk < 2; kk++)
                    acc[i][j] = SW
                        ? __builtin_amdgcn_mfma_f32_16x16x32_bf16(b0[j][kk], af[i][kk], acc[i][j], 0, 0, 0)
                        : __builtin_amdgcn_mfma_f32_16x16x32_bf16(af[i][kk], b0[j][kk], acc[i][j], 0, 0, 0);
        __builtin_amdgcn_s_setprio(0);
        asm volatile("" ::: "memory");
        __builtin_amdgcn_s_barrier();
        asm volatile("" ::: "memory");

        // ph1: read B1; MFMA (Alo,B1)
#pragma unroll
        for (int j = 0; j < 2; j++) {
            int r = wn * 64 + (2 + j) * 16 + l15;
            b1[j][0] = ldsr(&bs[r * 64 + ((quad ^ l7) * 8)]);
            b1[j][1] = ldsr(&bs[r * 64 + (((4 + quad) ^ l7) * 8)]);
        }
        asm volatile("" ::: "memory");
        __builtin_amdgcn_s_barrier();
        asm volatile("s_waitcnt lgkmcnt(0)" ::: "memory");
        __builtin_amdgcn_sched_barrier(0);
        __builtin_amdgcn_s_setprio(1);
#pragma unroll
        for (int i = 0; i < 4; i++)
#pragma unroll
            for (int j = 0; j < 2; j++)
#pragma unroll
                for (int kk = 0; kk < 2; kk++)
                    acc[i][2 + j] = SW
                        ? __builtin_amdgcn_mfma_f32_16x16x32_bf16(b1[j][kk], af[i][kk], acc[i][2 + j], 0, 0, 0)
                        : __builtin_amdgcn_mfma_f32_16x16x32_bf16(af[i][kk], b1[j][kk], acc[i][2 + j], 0, 0, 0);
        __builtin_amdgcn_s_setprio(0);
        asm volatile("" ::: "memory");
        __builtin_amdgcn_s_barrier();
        asm volatile("" ::: "memory");

        // ph2: read A-high; stage B(kt+2,h0); MFMA (Ahi,B1)
#pragma unroll
        for (int i = 0; i < 4; i++) {
            int r = wm * 128 + 64 + i * 16 + l15;
            af[i][0] = ldsr(&as[r * 64 + ((quad ^ l7) * 8)]);
            af[i][1] = ldsr(&as[r * 64 + (((4 + quad) ^ l7) * 8)]);
        }
        if (kt + 2 < NT) stageB(kt + 2, 0);
        asm volatile("" ::: "memory");
        __builtin_amdgcn_s_barrier();
        asm volatile("s_waitcnt lgkmcnt(0)" ::: "memory");
        __builtin_amdgcn_sched_barrier(0);
        __builtin_amdgcn_s_setprio(1);
#pragma unroll
        for (int i = 0; i < 4; i++)
#pragma unroll
            for (int j = 0; j < 2; j++)
#pragma unroll
                for (int kk = 0; kk < 2; kk++)
                    acc[4 + i][2 + j] = SW
                        ? __builtin_amdgcn_mfma_f32_16x16x32_bf16(b1[j][kk], af[i][kk], acc[4 + i][2 + j], 0, 0, 0)
                        : __builtin_amdgcn_mfma_f32_16x16x32_bf16(af[i][kk], b1[j][kk], acc[4 + i][2 + j], 0, 0, 0);
        __builtin_amdgcn_s_setprio(0);
        asm volatile("" ::: "memory");
        __builtin_amdgcn_s_barrier();
        asm volatile("" ::: "memory");

        // ph3: stage A(kt+2,h0)+B(kt+2,h1) (A reads done at ph2 barrier); MFMA (Ahi,B0)
        if (kt + 2 < NT) { stageA(kt + 2, 0); stageB(kt + 2, 1); }
        __builtin_amdgcn_s_setprio(1);
#pragma unroll
        for (int i = 0; i < 4; i++)
#pragma unroll
            for (int j = 0; j < 2; j++)
#pragma unroll
                for (int kk = 0; kk < 2; kk++)
                    acc[4 + i][j] = SW
                        ? __builtin_amdgcn_mfma_f32_16x16x32_bf16(b0[j][kk], af[i][kk], acc[4 + i][j], 0, 0, 0)
                        : __builtin_amdgcn_mfma_f32_16x16x32_bf16(af[i][kk], b0[j][kk], acc[4 + i][j], 0, 0, 0);
        __builtin_amdgcn_s_setprio(0);
        if (kt + 2 < NT) {
            asm volatile("s_waitcnt vmcnt(6)" ::: "memory");
        } else if (kt + 1 < NT) {
            asm volatile("s_waitcnt vmcnt(0)" ::: "memory");
        }
        __builtin_amdgcn_s_barrier();
        asm volatile("" ::: "memory");
    }
}

// ================= CORE 2: 256x128, BK=64, 8 waves, 3-buf counted (verified) =================
#define A3 (256 * 64)
#define B3 (128 * 64)
#define BUF3 (A3 + B3)

template <bool SW>
__device__ __forceinline__ void gemm_core256(const unsigned short* __restrict__ A,
                                             const unsigned short* __restrict__ Bt,
                                             unsigned short* lds,
                                             int m0, int n0, floatx4 (&acc)[8][2]) {
    const int K = 1024, NT = 16;
    int tid = threadIdx.x;
    int lane = tid & 63, wave = tid >> 6;   // 8 waves: 2 (M) x 4 (N)
    int wm = wave >> 2, wn = wave & 3;
    int quad = lane >> 4, l15 = lane & 15, l7 = l15 & 7;
    int rsub = lane >> 3;
    int gl = (lane & 7) ^ rsub;

    floatx4 zero4 = {0.f, 0.f, 0.f, 0.f};
#pragma unroll
    for (int i = 0; i < 8; i++)
#pragma unroll
        for (int j = 0; j < 2; j++) acc[i][j] = zero4;

    auto stage = [&](int kt, int b) {
        const unsigned short* Ag = A + (long)m0 * K + kt * 64;
        const unsigned short* Bg = Bt + (long)n0 * K + kt * 64;
        unsigned short* as = lds + b * BUF3;
        unsigned short* bs = as + A3;
#pragma unroll
        for (int p = 0; p < 4; p++) {
            int chunk = wave * 4 + p;
            gll16(&Ag[(chunk * 8 + rsub) * K + gl * 8], &as[chunk * 512 + lane * 8]);
        }
#pragma unroll
        for (int p = 0; p < 2; p++) {
            int chunk = wave * 2 + p;
            gll16(&Bg[(chunk * 8 + rsub) * K + gl * 8], &bs[chunk * 512 + lane * 8]);
        }
    };

    stage(0, 0);
    stage(1, 1);
    stage(2, 2);
    asm volatile("s_waitcnt vmcnt(12)" ::: "memory");
    __builtin_amdgcn_s_barrier();
    asm volatile("" ::: "memory");

    int buf = 0;
    for (int kt = 0; kt < NT; kt++) {
        const unsigned short* as = lds + buf * BUF3;
        const unsigned short* bs = as + A3;
        short8 bf[2][2], af[4][2], ag[4][2];
#pragma unroll
        for (int j = 0; j < 2; j++) {
            int rb = wn * 32 + j * 16 + l15;
#pragma unroll
            for (int kk = 0; kk < 2; kk++)
                bf[j][kk] = ldsr(&bs[rb * 64 + (((kk * 4 + quad) ^ l7) * 8)]);
        }
#pragma unroll
        for (int i = 0; i < 4; i++) {
            int r = wm * 128 + i * 16 + l15;
#pragma unroll
            for (int kk = 0; kk < 2; kk++)
                af[i][kk] = ldsr(&as[r * 64 + (((kk * 4 + quad) ^ l7) * 8)]);
        }
        __builtin_amdgcn_s_setprio(1);
#pragma unroll
        for (int i = 0; i < 4; i++)
#pragma unroll
            for (int j = 0; j < 2; j++)
#pragma unroll
                for (int kk = 0; kk < 2; kk++)
                    acc[i][j] = SW
                        ? __builtin_amdgcn_mfma_f32_16x16x32_bf16(bf[j][kk], af[i][kk], acc[i][j], 0, 0, 0)
                        : __builtin_amdgcn_mfma_f32_16x16x32_bf16(af[i][kk], bf[j][kk], acc[i][j], 0, 0, 0);
        __builtin_amdgcn_s_setprio(0);
#pragma unroll
        for (int i = 0; i < 4; i++) {
            int r = wm * 128 + 64 + i * 16 + l15;
#pragma unroll
            for (int kk = 0; kk < 2; kk++)
                ag[i][kk] = ldsr(&as[r * 64 + (((kk * 4 + quad) ^ l7) * 8)]);
        }
        __builtin_amdgcn_s_setprio(1);
#pragma unroll
        for (int i = 0; i < 4; i++)
#pragma unroll
            for (int j = 0; j < 2; j++)
#pragma unroll
                for (int kk = 0; kk < 2; kk++)
                    acc[4 + i][j] = SW
                        ? __builtin_amdgcn_mfma_f32_16x16x32_bf16(bf[j][kk], ag[i][kk], acc[4 + i][j], 0, 0, 0)
                        : __builtin_amdgcn_mfma_f32_16x16x32_bf16(ag[i][kk], bf[j][kk], acc[4 + i][j], 0, 0, 0);
        __builtin_amdgcn_s_setprio(0);
        asm volatile("" ::: "memory");
        __builtin_amdgcn_s_barrier();
        asm volatile("" ::: "memory");
        if (kt + 3 < NT) {
            stage(kt + 3, buf);
            asm volatile("s_waitcnt vmcnt(12)" ::: "memory");
        } else if (kt + 3 == NT) {
            asm volatile("s_waitcnt vmcnt(6)" ::: "memory");
        } else if (kt + 2 == NT) {
            asm volatile("s_waitcnt vmcnt(0)" ::: "memory");
        }
        __builtin_amdgcn_s_barrier();
        asm volatile("" ::: "memory");
        buf = (buf == 2) ? 0 : buf + 1;
    }
}

// ---------------- merged proj: grid 8x64; y<32 -> Q|K (256x256 core), else V (256x128) ----------------
__global__ __launch_bounds__(512, 2) void proj_kernel(
    const unsigned short* __restrict__ xb, const unsigned short* __restrict__ wt,
    const float* __restrict__ bq, const float* __restrict__ bk, const float* __restrict__ bv,
    unsigned short* __restrict__ qo, unsigned short* __restrict__ ko,
    unsigned short* __restrict__ vo) {
    extern __shared__ __align__(16) unsigned short smem[];
    int tid = threadIdx.x, lane = tid & 63, wave = tid >> 6;
    int wm = wave >> 2, wn = wave & 3, quad = lane >> 4, l15 = lane & 15;

    if (blockIdx.y < 32) {
        // -------- projA role: Q|K GEMM, N=2048, 256x256 tiles, 256 blocks --------
        int lid = blockIdx.y * 8 + blockIdx.x;
        int grp = lid & 7;
        int inner = lid >> 3;
        int my = grp * 4 + inner / 8;
        int mx = inner % 8;
        int m0 = my * 256, n0 = mx * 256;
        floatx4 acc[8][4];
        gemm_core256sq<true>(xb, wt, smem, m0, n0, acc);
        int which = n0 >> 10;
        const float* bias = which ? bk : bq;
        unsigned short* dst = which ? ko : qo;
        float sc = which ? 1.0f : SCLF;
#pragma unroll
        for (int mt = 0; mt < 8; mt++)
#pragma unroll
            for (int nt = 0; nt < 4; nt++) {
                int tok = m0 + wm * 128 + mt * 16 + l15;
                int b = tok >> 11, s = tok & 2047;
                int colf = (n0 + wn * 64 + nt * 16 + quad * 4) & 1023;
                float4 bb = *(const float4*)&bias[colf];
                int h = colf >> 6, dk = colf & 63;
                ushort4v o;
                o.x = f2bf((acc[mt][nt][0] + bb.x) * sc);
                o.y = f2bf((acc[mt][nt][1] + bb.y) * sc);
                o.z = f2bf((acc[mt][nt][2] + bb.z) * sc);
                o.w = f2bf((acc[mt][nt][3] + bb.w) * sc);
                *(ushort4v*)&dst[((long)((b * 16 + h) * 2048 + s)) * 64 + dk] = o;
            }
    } else {
        // -------- projB role: V GEMM, N=1024, 256x128 tiles, 256 blocks --------
        int lid = (blockIdx.y - 32) * 8 + blockIdx.x;
        int grp = lid & 7;
        int inner = lid >> 3;
        int my = grp * 4 + (inner & 3);
        int mx = inner >> 2;
        int m0 = my * 256, n0 = mx * 128 + 2048;   // V segment of wtq|wtk|wtv
        floatx4 acc[8][2];
        gemm_core256<false>(xb, wt, smem, m0, n0, acc);
#pragma unroll
        for (int mt = 0; mt < 8; mt++)
#pragma unroll
            for (int nt = 0; nt < 2; nt++) {
                int tok0 = m0 + wm * 128 + mt * 16 + quad * 4;
                int b = tok0 >> 11, s = tok0 & 2047;
                int colf = (n0 & 1023) + wn * 32 + nt * 16 + l15;
                int h = colf >> 6, dk = colf & 63;
                float bb = bv[colf];
                ushort4v o;
                o.x = f2bf(acc[mt][nt][0] + bb);
                o.y = f2bf(acc[mt][nt][1] + bb);
                o.z = f2bf(acc[mt][nt][2] + bb);
                o.w = f2bf(acc[mt][nt][3] + bb);
                *(ushort4v*)&vo[((long)((b * 16 + h) * 64 + dk)) * 2048 + s] = o;
            }
    }
}

// ---------------- output GEMM (swapped): fp32 out, 256x128, 256 blocks ----------------
__global__ __launch_bounds__(512, 2) void gemm_out_kernel(
    const unsigned short* __restrict__ ob, const unsigned short* __restrict__ wto,
    const float* __restrict__ bo, float* __restrict__ out) {
    extern __shared__ __align__(16) unsigned short smem[];
    int lid = blockIdx.y * 8 + blockIdx.x;
    int grp = lid & 7;
    int inner = lid >> 3;
    int my = grp * 4 + (inner & 3);
    int mx = inner >> 2;
    int m0 = my * 256, n0 = mx * 128;
    int tid = threadIdx.x, lane = tid & 63, wave = tid >> 6;
    int wm = wave >> 2, wn = wave & 3, quad = lane >> 4, l15 = lane & 15;
    floatx4 acc[8][2];
    gemm_core256<true>(ob, wto, smem, m0, n0, acc);

#pragma unroll
    for (int mt = 0; mt < 8; mt++)
#pragma unroll
        for (int nt = 0; nt < 2; nt++) {
            int tok = m0 + wm * 128 + mt * 16 + l15;
            int cg = n0 + wn * 32 + nt * 16 + quad * 4;
            float4 bb = *(const float4*)&bo[cg];
            float4 o;
            o.x = acc[mt][nt][0] + bb.x;
            o.y = acc[mt][nt][1] + bb.y;
            o.z = acc[mt][nt][2] + bb.z;
            o.w = acc[mt][nt][3] + bb.w;
            *(float4*)&out[(long)tok * 1024 + cg] = o;
        }
}

// ---------------- flash attention (causal), 128 q-rows/block (R7-verified) ----------------
__device__ __forceinline__ void stage_kv(const unsigned short* __restrict__ Kg,
                                         const unsigned short* __restrict__ Vg,
                                         unsigned short* Ks, unsigned short* Vs,
                                         int lane, int wave) {
    int rsub = lane >> 3;
    int g = (lane & 7) ^ rsub;
#pragma unroll
    for (int p = 0; p < 2; p++) {
        int chunk = wave * 2 + p;
        int r = chunk * 8 + rsub;
        gll16(&Kg[r * 64 + g * 8], &Ks[chunk * 512]);
        gll16(&Vg[r * 2048 + g * 8], &Vs[chunk * 512]);
    }
}

__global__ __launch_bounds__(256, 4) void attn_kernel(
    const unsigned short* __restrict__ Q, const unsigned short* __restrict__ Kk,
    const unsigned short* __restrict__ Vt, unsigned short* __restrict__ O) {
    __shared__ __align__(16) unsigned short Ks[2][8 * 512];
    __shared__ __align__(16) unsigned short Vs[2][8 * 512];
    __shared__ __align__(16) unsigned short Ps[4 * 16 * 64];

    int bid = blockIdx.x;
    // Load-balance perm: qt = nibble[bid>>6] of 0x765489AB3210CDEF.
    // CU class k (bids k*64.., round-robin) gets qt groups {m[k],m[k+4],m[k+8],m[k+12]}
    // summing to 30 -> 68 work units per CU (uniform). Heaviest groups first.
    int qt = (int)((0x765489AB3210CDEFull >> ((bid >> 6) * 4)) & 15);
    int bh = bid & 63;
    int q0 = qt * 128;
    long base = (long)bh * 2048 * 64;
    long vbase = (long)bh * 64 * 2048;
    int tid = threadIdx.x, lane = tid & 63, wave = tid >> 6;
    int quad = lane >> 4, l15 = lane & 15, l7 = l15 & 7;

    short8 qfA[2], qfB[2];
    int qrA = q0 + wave * 16 + l15;
    int qrB = qrA + 64;
    qfA[0] = *(const short8*)&Q[base + qrA * 64 + quad * 8];
    qfA[1] = *(const short8*)&Q[base + qrA * 64 + 32 + quad * 8];
    qfB[0] = *(const short8*)&Q[base + qrB * 64 + quad * 8];
    qfB[1] = *(const short8*)&Q[base + qrB * 64 + 32 + quad * 8];

    float lA = 0.f, lB = 0.f;
    floatx4 oA[4], oB[4];
    floatx4 zero4 = {0.f, 0.f, 0.f, 0.f};
#pragma unroll
    for (int st = 0; st < 4; st++) { oA[st] = zero4; oB[st] = zero4; }

    unsigned short* myP = &Ps[(wave * 16) * 64];
    int pw_off = l15 * 64 + (quad & 1) * 4;
    int pr0 = l15 * 64 + ((quad ^ l7) * 8);
    int pr1 = l15 * 64 + (((4 + quad) ^ l7) * 8);

    int ktmax = 2 * qt + 1;
    stage_kv(&Kk[base], &Vt[vbase], Ks[0], Vs[0], lane, wave);
    __syncthreads();

    for (int kt = 0; kt <= ktmax; kt++) {
        int cur = kt & 1;
        if (kt < ktmax)
            stage_kv(&Kk[base + (long)(kt + 1) * 64 * 64], &Vt[vbase + (kt + 1) * 64],
                     Ks[cur ^ 1], Vs[cur ^ 1], lane, wave);
        bool doA = (kt < ktmax);
        bool maskA = (kt == ktmax - 1);
        bool maskB = (kt == ktmax);

        floatx4 saA[4], saB[4];
#pragma unroll
        for (int st = 0; st < 4; st++) {
            int row = st * 16 + l15;
            short8 kf0 = ldsr(&Ks[cur][row * 64 + ((quad ^ l7) * 8)]);
            short8 kf1 = ldsr(&Ks[cur][row * 64 + (((4 + quad) ^ l7) * 8)]);
            saB[st] = __builtin_amdgcn_mfma_f32_16x16x32_bf16(kf0, qfB[0], zero4, 0, 0, 0);
            saB[st] = __builtin_amdgcn_mfma_f32_16x16x32_bf16(kf1, qfB[1], saB[st], 0, 0, 0);
            if (doA) {
                saA[st] = __builtin_amdgcn_mfma_f32_16x16x32_bf16(kf0, qfA[0], zero4, 0, 0, 0);
                saA[st] = __builtin_amdgcn_mfma_f32_16x16x32_bf16(kf1, qfA[1], saA[st], 0, 0, 0);
            }
        }

        int kg0 = kt * 64 + quad * 4;
        short8 pfB0, pfB1, pfA0, pfA1;
        {
            float p[4][4];
#pragma unroll
            for (int st = 0; st < 4; st++)
#pragma unroll
                for (int r = 0; r < 4; r++)
                    p[st][r] = __builtin_amdgcn_exp2f(saB[st][r]);
            if (maskB) {
#pragma unroll
                for (int st = 0; st < 4; st++)
#pragma unroll
                    for (int r = 0; r < 4; r++)
                        if (kg0 + st * 16 + r > qrB) p[st][r] = 0.f;
            }
            float rs = 0.f;
#pragma unroll
            for (int st = 0; st < 4; st++) {
                rs += p[st][0] + p[st][1] + p[st][2] + p[st][3];
                uint2 pw;
                pw.x = pk2bf(p[st][0], p[st][1]);
                pw.y = pk2bf(p[st][2], p[st][3]);
                *(uint2*)&myP[pw_off + (((st * 2 + (quad >> 1)) ^ l7) * 8)] = pw;
            }
            rs += __shfl_xor(rs, 16, 64);
            rs += __shfl_xor(rs, 32, 64);
            lB += rs;
            pfB0 = ldsr(&myP[pr0]);
            pfB1 = ldsr(&myP[pr1]);
        }
        if (doA) {
            float p[4][4];
#pragma unroll
            for (int st = 0; st < 4; st++)
#pragma unroll
                for (int r = 0; r < 4; r++)
                    p[st][r] = __builtin_amdgcn_exp2f(saA[st][r]);
            if (maskA) {
#pragma unroll
                for (int st = 0; st < 4; st++)
#pragma unroll
                    for (int r = 0; r < 4; r++)
                        if (kg0 + st * 16 + r > qrA) p[st][r] = 0.f;
            }
            float rs = 0.f;
#pragma unroll
            for (int st = 0; st < 4; st++) {
                rs += p[st][0] + p[st][1] + p[st][2] + p[st][3];
                uint2 pw;
                pw.x = pk2bf(p[st][0], p[st][1]);
                pw.y = pk2bf(p[st][2], p[st][3]);
                *(uint2*)&myP[pw_off + (((st * 2 + (quad >> 1)) ^ l7) * 8)] = pw;
            }
            rs += __shfl_xor(rs, 16, 64);
            rs += __shfl_xor(rs, 32, 64);
            lA += rs;
            pfA0 = ldsr(&myP[pr0]);
            pfA1 = ldsr(&myP[pr1]);
        }

#pragma unroll
        for (int st = 0; st < 4; st++) {
            int row = st * 16 + l15;
            short8 vf0 = ldsr(&Vs[cur][row * 64 + ((quad ^ l7) * 8)]);
            short8 vf1 = ldsr(&Vs[cur][row * 64 + (((4 + quad) ^ l7) * 8)]);
            oB[st] = __builtin_amdgcn_mfma_f32_16x16x32_bf16(vf0, pfB0, oB[st], 0, 0, 0);
            oB[st] = __builtin_amdgcn_mfma_f32_16x16x32_bf16(vf1, pfB1, oB[st], 0, 0, 0);
            if (doA) {
                oA[st] = __builtin_amdgcn_mfma_f32_16x16x32_bf16(vf0, pfA0, oA[st], 0, 0, 0);
                oA[st] = __builtin_amdgcn_mfma_f32_16x16x32_bf16(vf1, pfA1, oA[st], 0, 0, 0);
            }
        }
        __syncthreads();
    }

    int b = bh >> 4, h = bh & 15;
    float invA = 1.f / lA, invB = 1.f / lB;
#pragma unroll
    for (int st = 0; st < 4; st++) {
        uint2 ov;
        ov.x = pk2bf(oA[st][0] * invA, oA[st][1] * invA);
        ov.y = pk2bf(oA[st][2] * invA, oA[st][3] * invA);
        *(uint2*)&O[((long)(b * 2048 + qrA)) * 1024 + h * 64 + st * 16 + quad * 4] = ov;
        uint2 ow;
        ow.x = pk2bf(oB[st][0] * invB, oB[st][1] * invB);
        ow.y = pk2bf(oB[st][2] * invB, oB[st][3] * invB);
        *(uint2*)&O[((long)(b * 2048 + qrB)) * 1024 + h * 64 + st * 16 + quad * 4] = ow;
    }
}

// ---------------- launch ----------------
extern "C" void kernel_launch(void* const* d_in, const int* in_sizes, int n_in,
                              void* d_out, int out_size, void* d_ws, size_t ws_size,
                              hipStream_t stream) {
    const float* x  = (const float*)d_in[0];
    const float* wq = (const float*)d_in[1];
    const float* bq = (const float*)d_in[2];
    const float* wk = (const float*)d_in[3];
    const float* bk = (const float*)d_in[4];
    const float* wv = (const float*)d_in[5];
    const float* bv = (const float*)d_in[6];
    const float* wo = (const float*)d_in[7];
    const float* bo = (const float*)d_in[8];

    char* w = (char*)d_ws;
    unsigned short* xb  = (unsigned short*)w;                    // 16MB
    unsigned short* wtq = (unsigned short*)(w + (16u << 20));    // wtq|wtk|wtv|wto contiguous
    unsigned short* wto = wtq + (3u << 20);
    unsigned short* qb  = wto + (1u << 20);
    unsigned short* kb  = qb + (8u << 20);
    unsigned short* vb  = kb + (8u << 20);                       // V^T [B,H,DK,S]
    unsigned short* ob  = vb + (8u << 20);

    prep_kernel<<<12288, 256, 0, stream>>>(x, xb, wq, wk, wv, wo, wtq);
    proj_kernel<<<dim3(8, 64), 512, 144 * 1024, stream>>>(xb, wtq, bq, bk, bv, qb, kb, vb);
    attn_kernel<<<1024, 256, 0, stream>>>(qb, kb, vb, ob);
    gemm_out_kernel<<<dim3(8, 32), 512, 144 * 1024, stream>>>(ob, wto, bo, (float*)d_out);
}

// Round 15
// 248.759 us; speedup vs baseline: 1.0163x; 1.0163x over previous
//
#include <hip/hip_runtime.h>

// MultiHeadAttention: B=4, S=2048, D=1024, H=16, DK=64
// FINAL (R15 = R14): 4 dispatches — prep (cvtx+wtrans), proj (Q|K 256x256
// 4-phase core + V 256x128 3-buf core merged, grid 8x64, backfill overlap),
// flash attention (R7 structure + qt balance perm), output GEMM.
// Session adjudication: 4-phase 256sq core + packed 256-block grids (R5/R6),
// qt perm (R7) and proj merge (R14) are the wins; R8/R9/R11 attn
// restructures regressed and were reverted. Residual total-vs-kernel-sum
// (~80us) is fixed harness overhead, not dispatch-count (R14 null).

typedef __attribute__((ext_vector_type(8))) short short8;
typedef __attribute__((ext_vector_type(4))) float floatx4;
typedef __attribute__((ext_vector_type(4))) unsigned short ushort4v;

#define SCLF (0.125f * 1.44269504f)

__device__ __forceinline__ unsigned short f2bf(float f) {
    unsigned int u = __float_as_uint(f);
    unsigned int r = (u + 0x7fffu + ((u >> 16) & 1u)) >> 16;
    return (unsigned short)r;
}

__device__ __forceinline__ unsigned int pk2bf(float lo, float hi) {
    return __builtin_amdgcn_perm(__float_as_uint(hi), __float_as_uint(lo), 0x07060302u);
}

__device__ __forceinline__ void gll16(const unsigned short* g, unsigned short* l) {
    __builtin_amdgcn_global_load_lds(
        (const __attribute__((address_space(1))) unsigned int*)g,
        (__attribute__((address_space(3))) unsigned int*)l, 16, 0, 0);
}

// ---------------- prep: cvtx (blocks 0..8191) + wtrans (blocks 8192..12287) ----------------
__global__ void prep_kernel(const float* __restrict__ x, unsigned short* __restrict__ xb,
                            const float* __restrict__ wq, const float* __restrict__ wk,
                            const float* __restrict__ wv, const float* __restrict__ wo,
                            unsigned short* __restrict__ wtbase) {
    __shared__ float t[32][33];
    int blk = blockIdx.x;
    if (blk < 8192) {
        int i = (blk * 256 + threadIdx.x) * 4;
        float4 v = *(const float4*)&x[i];
        ushort4v o;
        o.x = f2bf(v.x); o.y = f2bf(v.y); o.z = f2bf(v.z); o.w = f2bf(v.w);
        *(ushort4v*)&xb[i] = o;
    } else {
        int bb = blk - 8192;
        int z = bb >> 10;            // 1024 blocks per weight
        int rem = bb & 1023;
        int by = rem >> 5, bx = rem & 31;
        const float* w = (z == 0) ? wq : (z == 1) ? wk : (z == 2) ? wv : wo;
        unsigned short* wt = wtbase + ((long)z << 20);
        int kb = by * 32, nb = bx * 32;
        int col = threadIdx.x & 31, rw = threadIdx.x >> 5;
#pragma unroll
        for (int i = 0; i < 4; i++) {
            int row = rw + i * 8;
            t[row][col] = w[(kb + row) * 1024 + nb + col];
        }
        __syncthreads();
#pragma unroll
        for (int i = 0; i < 4; i++) {
            int row = rw + i * 8;
            wt[(nb + row) * 1024 + kb + col] = f2bf(t[col][row]);
        }
    }
}

__device__ __forceinline__ short8 ldsr(const unsigned short* p) { return *(const short8*)p; }

// ================= CORE 1: 256x256, BK=64, 8 waves, 4-phase (verified) =================
#define ASQ (256 * 64)
#define BUFSQ (2 * ASQ)

template <bool SW>
__device__ __forceinline__ void gemm_core256sq(const unsigned short* __restrict__ A,
                                               const unsigned short* __restrict__ Bt,
                                               unsigned short* lds,
                                               int m0, int n0, floatx4 (&acc)[8][4]) {
    const int K = 1024, NT = 16;
    int tid = threadIdx.x;
    int lane = tid & 63, wave = tid >> 6;   // 8 waves: 2 (M) x 4 (N)
    int wm = wave >> 2, wn = wave & 3;      // per-wave C: 128x64
    int quad = lane >> 4, l15 = lane & 15, l7 = l15 & 7;
    int rsub = lane >> 3;
    int gl = (lane & 7) ^ rsub;

    floatx4 zero4 = {0.f, 0.f, 0.f, 0.f};
#pragma unroll
    for (int i = 0; i < 8; i++)
#pragma unroll
        for (int j = 0; j < 4; j++) acc[i][j] = zero4;

    auto stageA = [&](int kt, int half) {
        const unsigned short* Ag = A + (long)m0 * K + kt * 64;
        unsigned short* as = lds + (kt & 1) * BUFSQ;
#pragma unroll
        for (int p = 0; p < 2; p++) {
            int chunk = half * 16 + wave * 2 + p;
            gll16(&Ag[(chunk * 8 + rsub) * K + gl * 8], &as[chunk * 512 + lane * 8]);
        }
    };
    auto stageB = [&](int kt, int half) {
        const unsigned short* Bg = Bt + (long)n0 * K + kt * 64;
        unsigned short* bs = lds + (kt & 1) * BUFSQ + ASQ;
#pragma unroll
        for (int p = 0; p < 2; p++) {
            int chunk = half * 16 + wave * 2 + p;
            gll16(&Bg[(chunk * 8 + rsub) * K + gl * 8], &bs[chunk * 512 + lane * 8]);
        }
    };

    stageA(0, 0); stageA(0, 1); stageB(0, 0); stageB(0, 1);
    stageB(1, 0); stageA(1, 0); stageB(1, 1);
    asm volatile("s_waitcnt vmcnt(6)" ::: "memory");
    __builtin_amdgcn_s_barrier();
    asm volatile("" ::: "memory");

    short8 af[4][2], b0[2][2], b1[2][2];

    for (int kt = 0; kt < NT; kt++) {
        const unsigned short* as = lds + (kt & 1) * BUFSQ;
        const unsigned short* bs = as + ASQ;

        // ph0: read A-low + B0; stage A(kt+1,h1) (other buffer); MFMA (Alo,B0)
#pragma unroll
        for (int i = 0; i < 4; i++) {
            int r = wm * 128 + i * 16 + l15;
            af[i][0] = ldsr(&as[r * 64 + ((quad ^ l7) * 8)]);
            af[i][1] = ldsr(&as[r * 64 + (((4 + quad) ^ l7) * 8)]);
        }
#pragma unroll
        for (int j = 0; j < 2; j++) {
            int r = wn * 64 + j * 16 + l15;
            b0[j][0] = ldsr(&bs[r * 64 + ((quad ^ l7) * 8)]);
            b0[j][1] = ldsr(&bs[r * 64 + (((4 + quad) ^ l7) * 8)]);
        }
        if (kt + 1 < NT) stageA(kt + 1, 1);
        asm volatile("" ::: "memory");
        __builtin_amdgcn_s_barrier();
        asm volatile("s_waitcnt lgkmcnt(0)" ::: "memory");
        __builtin_amdgcn_sched_barrier(0);
        __builtin_amdgcn_s_setprio(1);
#pragma unroll
        for (int i = 0; i < 4; i++)
#pragma unroll
            for (int j = 0; j < 2; j++)
#pragma unroll
                for (int kk = 0; kk < 2; kk++)
                    acc[i][j] = SW
                        ? __builtin_amdgcn_mfma_f32_16x16x32_bf16(b0[j][kk], af[i][kk], acc[i][j], 0, 0, 0)
                        : __builtin_amdgcn_mfma_f32_16x16x32_bf16(af[i][kk], b0[j][kk], acc[i][j], 0, 0, 0);
        __builtin_amdgcn_s_setprio(0);
        asm volatile("" ::: "memory");
        __builtin_amdgcn_s_barrier();
        asm volatile("" ::: "memory");

        // ph1: read B1; MFMA (Alo,B1)
#pragma unroll
        for (int j = 0; j < 2; j++) {
            int r = wn * 64 + (2 + j) * 16 + l15;
            b1[j][0] = ldsr(&bs[r * 64 + ((quad ^ l7) * 8)]);
            b1[j][1] = ldsr(&bs[r * 64 + (((4 + quad) ^ l7) * 8)]);
        }
        asm volatile("" ::: "memory");
        __builtin_amdgcn_s_barrier();
        asm volatile("s_waitcnt lgkmcnt(0)" ::: "memory");
        __builtin_amdgcn_sched_barrier(0);
        __builtin_amdgcn_s_setprio(1);
#pragma unroll
        for (int i = 0; i < 4; i++)
#pragma unroll
            for (int j = 0; j < 2; j++)
#pragma unroll
                for (int kk = 0; kk < 2; kk++)
                    acc[i][2 + j] = SW
                        ? __builtin_amdgcn_mfma_f32_16x16x32_bf16(b1[j][kk], af[i][kk], acc[i][2 + j], 0, 0, 0)
                        : __builtin_amdgcn_mfma_f32_16x16x32_bf16(af[i][kk], b1[j][kk], acc[i][2 + j], 0, 0, 0);
        __builtin_amdgcn_s_setprio(0);
        asm volatile("" ::: "memory");
        __builtin_amdgcn_s_barrier();
        asm volatile("" ::: "memory");

        // ph2: read A-high; stage B(kt+2,h0); MFMA (Ahi,B1)
#pragma unroll
        for (int i = 0; i < 4; i++) {
            int r = wm * 128 + 64 + i * 16 + l15;
            af[i][0] = ldsr(&as[r * 64 + ((quad ^ l7) * 8)]);
            af[i][1] = ldsr(&as[r * 64 + (((4 + quad) ^ l7) * 8)]);
        }
        if (kt + 2 < NT) stageB(kt + 2, 0);
        asm volatile("" ::: "memory");
        __builtin_amdgcn_s_barrier();
        asm volatile("s_waitcnt lgkmcnt(0)" ::: "memory");
        __builtin_amdgcn_sched_barrier(0);
        __builtin_amdgcn_s_setprio(1);
#pragma unroll
        for (int i = 0; i < 4; i++)
#pragma unroll
            for (int j = 0; j < 2; j++)
#pragma unroll
                for (int kk = 0; kk < 2; kk++)
                    acc[4 + i][2 + j] = SW
                        ? __builtin_amdgcn_mfma_f32_16x16x32_bf16(b1[j][kk], af[i][kk], acc[4 + i][2 + j], 0, 0, 0)
                        : __builtin_amdgcn_mfma_f32_16x16x32_bf16(af[i][kk], b1[j][kk], acc[4 + i][2 + j], 0, 0, 0);
        __builtin_amdgcn_s_setprio(0);
        asm volatile("" ::: "memory");
        __builtin_amdgcn_s_barrier();
        asm volatile("" ::: "memory");

        // ph3: stage A(kt+2,h0)+B(kt+2,h1) (A reads done at ph2 barrier); MFMA (Ahi,B0)
        if (kt + 2 < NT) { stageA(kt + 2, 0); stageB(kt + 2, 1); }
        __builtin_amdgcn_s_setprio(1);
#pragma unroll
        for (int i = 0; i < 4; i++)
#pragma unroll
            for (int j = 0; j < 2; j++)
#pragma unroll
                for (int kk = 0; kk < 2; kk++)
                    acc[4 + i][j] = SW
                        ? __builtin_amdgcn_mfma_f32_16x16x32_bf16(b0[j][kk], af[i][kk], acc[4 + i][j], 0, 0, 0)
                        : __builtin_amdgcn_mfma_f32_16x16x32_bf16(af[i][kk], b0[j][kk], acc[4 + i][j], 0, 0, 0);
        __builtin_amdgcn_s_setprio(0);
        if (kt + 2 < NT) {
            asm volatile("s_waitcnt vmcnt(6)" ::: "memory");
        } else if (kt + 1 < NT) {
            asm volatile("s_waitcnt vmcnt(0)" ::: "memory");
        }
        __builtin_amdgcn_s_barrier();
        asm volatile("" ::: "memory");
    }
}

// ================= CORE 2: 256x128, BK=64, 8 waves, 3-buf counted (verified) =================
#define A3 (256 * 64)
#define B3 (128 * 64)
#define BUF3 (A3 + B3)

template <bool SW>
__device__ __forceinline__ void gemm_core256(const unsigned short* __restrict__ A,
                                             const unsigned short* __restrict__ Bt,
                                             unsigned short* lds,
                                             int m0, int n0, floatx4 (&acc)[8][2]) {
    const int K = 1024, NT = 16;
    int tid = threadIdx.x;
    int lane = tid & 63, wave = tid >> 6;   // 8 waves: 2 (M) x 4 (N)
    int wm = wave >> 2, wn = wave & 3;
    int quad = lane >> 4, l15 = lane & 15, l7 = l15 & 7;
    int rsub = lane >> 3;
    int gl = (lane & 7) ^ rsub;

    floatx4 zero4 = {0.f, 0.f, 0.f, 0.f};
#pragma unroll
    for (int i = 0; i < 8; i++)
#pragma unroll
        for (int j = 0; j < 2; j++) acc[i][j] = zero4;

    auto stage = [&](int kt, int b) {
        const unsigned short* Ag = A + (long)m0 * K + kt * 64;
        const unsigned short* Bg = Bt + (long)n0 * K + kt * 64;
        unsigned short* as = lds + b * BUF3;
        unsigned short* bs = as + A3;
#pragma unroll
        for (int p = 0; p < 4; p++) {
            int chunk = wave * 4 + p;
            gll16(&Ag[(chunk * 8 + rsub) * K + gl * 8], &as[chunk * 512 + lane * 8]);
        }
#pragma unroll
        for (int p = 0; p < 2; p++) {
            int chunk = wave * 2 + p;
            gll16(&Bg[(chunk * 8 + rsub) * K + gl * 8], &bs[chunk * 512 + lane * 8]);
        }
    };

    stage(0, 0);
    stage(1, 1);
    stage(2, 2);
    asm volatile("s_waitcnt vmcnt(12)" ::: "memory");
    __builtin_amdgcn_s_barrier();
    asm volatile("" ::: "memory");

    int buf = 0;
    for (int kt = 0; kt < NT; kt++) {
        const unsigned short* as = lds + buf * BUF3;
        const unsigned short* bs = as + A3;
        short8 bf[2][2], af[4][2], ag[4][2];
#pragma unroll
        for (int j = 0; j < 2; j++) {
            int rb = wn * 32 + j * 16 + l15;
#pragma unroll
            for (int kk = 0; kk < 2; kk++)
                bf[j][kk] = ldsr(&bs[rb * 64 + (((kk * 4 + quad) ^ l7) * 8)]);
        }
#pragma unroll
        for (int i = 0; i < 4; i++) {
            int r = wm * 128 + i * 16 + l15;
#pragma unroll
            for (int kk = 0; kk < 2; kk++)
                af[i][kk] = ldsr(&as[r * 64 + (((kk * 4 + quad) ^ l7) * 8)]);
        }
        __builtin_amdgcn_s_setprio(1);
#pragma unroll
        for (int i = 0; i < 4; i++)
#pragma unroll
            for (int j = 0; j < 2; j++)
#pragma unroll
                for (int kk = 0; kk < 2; kk++)
                    acc[i][j] = SW
                        ? __builtin_amdgcn_mfma_f32_16x16x32_bf16(bf[j][kk], af[i][kk], acc[i][j], 0, 0, 0)
                        : __builtin_amdgcn_mfma_f32_16x16x32_bf16(af[i][kk], bf[j][kk], acc[i][j], 0, 0, 0);
        __builtin_amdgcn_s_setprio(0);
#pragma unroll
        for (int i = 0; i < 4; i++) {
            int r = wm * 128 + 64 + i * 16 + l15;
#pragma unroll
            for (int kk = 0; kk < 2; kk++)
                ag[i][kk] = ldsr(&as[r * 64 + (((kk * 4 + quad) ^ l7) * 8)]);
        }
        __builtin_amdgcn_s_setprio(1);
#pragma unroll
        for (int i = 0; i < 4; i++)
#pragma unroll
            for (int j = 0; j < 2; j++)
#pragma unroll
                for (int kk = 0; kk < 2; kk++)
                    acc[4 + i][j] = SW
                        ? __builtin_amdgcn_mfma_f32_16x16x32_bf16(bf[j][kk], ag[i][kk], acc[4 + i][j], 0, 0, 0)
                        : __builtin_amdgcn_mfma_f32_16x16x32_bf16(ag[i][kk], bf[j][kk], acc[4 + i][j], 0, 0, 0);
        __builtin_amdgcn_s_setprio(0);
        asm volatile("" ::: "memory");
        __builtin_amdgcn_s_barrier();
        asm volatile("" ::: "memory");
        if (kt + 3 < NT) {
            stage(kt + 3, buf);
            asm volatile("s_waitcnt vmcnt(12)" ::: "memory");
        } else if (kt + 3 == NT) {
            asm volatile("s_waitcnt vmcnt(6)" ::: "memory");
        } else if (kt + 2 == NT) {
            asm volatile("s_waitcnt vmcnt(0)" ::: "memory");
        }
        __builtin_amdgcn_s_barrier();
        asm volatile("" ::: "memory");
        buf = (buf == 2) ? 0 : buf + 1;
    }
}

// ---------------- merged proj: grid 8x64; y<32 -> Q|K (256x256 core), else V (256x128) ----------------
__global__ __launch_bounds__(512, 2) void proj_kernel(
    const unsigned short* __restrict__ xb, const unsigned short* __restrict__ wt,
    const float* __restrict__ bq, const float* __restrict__ bk, const float* __restrict__ bv,
    unsigned short* __restrict__ qo, unsigned short* __restrict__ ko,
    unsigned short* __restrict__ vo) {
    extern __shared__ __align__(16) unsigned short smem[];
    int tid = threadIdx.x, lane = tid & 63, wave = tid >> 6;
    int wm = wave >> 2, wn = wave & 3, quad = lane >> 4, l15 = lane & 15;

    if (blockIdx.y < 32) {
        // -------- projA role: Q|K GEMM, N=2048, 256x256 tiles, 256 blocks --------
        int lid = blockIdx.y * 8 + blockIdx.x;
        int grp = lid & 7;
        int inner = lid >> 3;
        int my = grp * 4 + inner / 8;
        int mx = inner % 8;
        int m0 = my * 256, n0 = mx * 256;
        floatx4 acc[8][4];
        gemm_core256sq<true>(xb, wt, smem, m0, n0, acc);
        int which = n0 >> 10;
        const float* bias = which ? bk : bq;
        unsigned short* dst = which ? ko : qo;
        float sc = which ? 1.0f : SCLF;
#pragma unroll
        for (int mt = 0; mt < 8; mt++)
#pragma unroll
            for (int nt = 0; nt < 4; nt++) {
                int tok = m0 + wm * 128 + mt * 16 + l15;
                int b = tok >> 11, s = tok & 2047;
                int colf = (n0 + wn * 64 + nt * 16 + quad * 4) & 1023;
                float4 bb = *(const float4*)&bias[colf];
                int h = colf >> 6, dk = colf & 63;
                ushort4v o;
                o.x = f2bf((acc[mt][nt][0] + bb.x) * sc);
                o.y = f2bf((acc[mt][nt][1] + bb.y) * sc);
                o.z = f2bf((acc[mt][nt][2] + bb.z) * sc);
                o.w = f2bf((acc[mt][nt][3] + bb.w) * sc);
                *(ushort4v*)&dst[((long)((b * 16 + h) * 2048 + s)) * 64 + dk] = o;
            }
    } else {
        // -------- projB role: V GEMM, N=1024, 256x128 tiles, 256 blocks --------
        int lid = (blockIdx.y - 32) * 8 + blockIdx.x;
        int grp = lid & 7;
        int inner = lid >> 3;
        int my = grp * 4 + (inner & 3);
        int mx = inner >> 2;
        int m0 = my * 256, n0 = mx * 128 + 2048;   // V segment of wtq|wtk|wtv
        floatx4 acc[8][2];
        gemm_core256<false>(xb, wt, smem, m0, n0, acc);
#pragma unroll
        for (int mt = 0; mt < 8; mt++)
#pragma unroll
            for (int nt = 0; nt < 2; nt++) {
                int tok0 = m0 + wm * 128 + mt * 16 + quad * 4;
                int b = tok0 >> 11, s = tok0 & 2047;
                int colf = (n0 & 1023) + wn * 32 + nt * 16 + l15;
                int h = colf >> 6, dk = colf & 63;
                float bb = bv[colf];
                ushort4v o;
                o.x = f2bf(acc[mt][nt][0] + bb);
                o.y = f2bf(acc[mt][nt][1] + bb);
                o.z = f2bf(acc[mt][nt][2] + bb);
                o.w = f2bf(acc[mt][nt][3] + bb);
                *(ushort4v*)&vo[((long)((b * 16 + h) * 64 + dk)) * 2048 + s] = o;
            }
    }
}

// ---------------- output GEMM (swapped): fp32 out, 256x128, 256 blocks ----------------
__global__ __launch_bounds__(512, 2) void gemm_out_kernel(
    const unsigned short* __restrict__ ob, const unsigned short* __restrict__ wto,
    const float* __restrict__ bo, float* __restrict__ out) {
    extern __shared__ __align__(16) unsigned short smem[];
    int lid = blockIdx.y * 8 + blockIdx.x;
    int grp = lid & 7;
    int inner = lid >> 3;
    int my = grp * 4 + (inner & 3);
    int mx = inner >> 2;
    int m0 = my * 256, n0 = mx * 128;
    int tid = threadIdx.x, lane = tid & 63, wave = tid >> 6;
    int wm = wave >> 2, wn = wave & 3, quad = lane >> 4, l15 = lane & 15;
    floatx4 acc[8][2];
    gemm_core256<true>(ob, wto, smem, m0, n0, acc);

#pragma unroll
    for (int mt = 0; mt < 8; mt++)
#pragma unroll
        for (int nt = 0; nt < 2; nt++) {
            int tok = m0 + wm * 128 + mt * 16 + l15;
            int cg = n0 + wn * 32 + nt * 16 + quad * 4;
            float4 bb = *(const float4*)&bo[cg];
            float4 o;
            o.x = acc[mt][nt][0] + bb.x;
            o.y = acc[mt][nt][1] + bb.y;
            o.z = acc[mt][nt][2] + bb.z;
            o.w = acc[mt][nt][3] + bb.w;
            *(float4*)&out[(long)tok * 1024 + cg] = o;
        }
}

// ---------------- flash attention (causal), 128 q-rows/block (R7-verified) ----------------
__device__ __forceinline__ void stage_kv(const unsigned short* __restrict__ Kg,
                                         const unsigned short* __restrict__ Vg,
                                         unsigned short* Ks, unsigned short* Vs,
                                         int lane, int wave) {
    int rsub = lane >> 3;
    int g = (lane & 7) ^ rsub;
#pragma unroll
    for (int p = 0; p < 2; p++) {
        int chunk = wave * 2 + p;
        int r = chunk * 8 + rsub;
        gll16(&Kg[r * 64 + g * 8], &Ks[chunk * 512]);
        gll16(&Vg[r * 2048 + g * 8], &Vs[chunk * 512]);
    }
}

__global__ __launch_bounds__(256, 4) void attn_kernel(
    const unsigned short* __restrict__ Q, const unsigned short* __restrict__ Kk,
    const unsigned short* __restrict__ Vt, unsigned short* __restrict__ O) {
    __shared__ __align__(16) unsigned short Ks[2][8 * 512];
    __shared__ __align__(16) unsigned short Vs[2][8 * 512];
    __shared__ __align__(16) unsigned short Ps[4 * 16 * 64];

    int bid = blockIdx.x;
    // Load-balance perm: qt = nibble[bid>>6] of 0x765489AB3210CDEF.
    // CU class k (bids k*64.., round-robin) gets qt groups {m[k],m[k+4],m[k+8],m[k+12]}
    // summing to 30 -> 68 work units per CU (uniform). Heaviest groups first.
    int qt = (int)((0x765489AB3210CDEFull >> ((bid >> 6) * 4)) & 15);
    int bh = bid & 63;
    int q0 = qt * 128;
    long base = (long)bh * 2048 * 64;
    long vbase = (long)bh * 64 * 2048;
    int tid = threadIdx.x, lane = tid & 63, wave = tid >> 6;
    int quad = lane >> 4, l15 = lane & 15, l7 = l15 & 7;

    short8 qfA[2], qfB[2];
    int qrA = q0 + wave * 16 + l15;
    int qrB = qrA + 64;
    qfA[0] = *(const short8*)&Q[base + qrA * 64 + quad * 8];
    qfA[1] = *(const short8*)&Q[base + qrA * 64 + 32 + quad * 8];
    qfB[0] = *(const short8*)&Q[base + qrB * 64 + quad * 8];
    qfB[1] = *(const short8*)&Q[base + qrB * 64 + 32 + quad * 8];

    float lA = 0.f, lB = 0.f;
    floatx4 oA[4], oB[4];
    floatx4 zero4 = {0.f, 0.f, 0.f, 0.f};
#pragma unroll
    for (int st = 0; st < 4; st++) { oA[st] = zero4; oB[st] = zero4; }

    unsigned short* myP = &Ps[(wave * 16) * 64];
    int pw_off = l15 * 64 + (quad & 1) * 4;
    int pr0 = l15 * 64 + ((quad ^ l7) * 8);
    int pr1 = l15 * 64 + (((4 + quad) ^ l7) * 8);

    int ktmax = 2 * qt + 1;
    stage_kv(&Kk[base], &Vt[vbase], Ks[0], Vs[0], lane, wave);
    __syncthreads();

    for (int kt = 0; kt <= ktmax; kt++) {
        int cur = kt & 1;
        if (kt < ktmax)
            stage_kv(&Kk[base + (long)(kt + 1) * 64 * 64], &Vt[vbase + (kt + 1) * 64],
                     Ks[cur ^ 1], Vs[cur ^ 1], lane, wave);
        bool doA = (kt < ktmax);
        bool maskA = (kt == ktmax - 1);
        bool maskB = (kt == ktmax);

        floatx4 saA[4], saB[4];
#pragma unroll
        for (int st = 0; st < 4; st++) {
            int row = st * 16 + l15;
            short8 kf0 = ldsr(&Ks[cur][row * 64 + ((quad ^ l7) * 8)]);
            short8 kf1 = ldsr(&Ks[cur][row * 64 + (((4 + quad) ^ l7) * 8)]);
            saB[st] = __builtin_amdgcn_mfma_f32_16x16x32_bf16(kf0, qfB[0], zero4, 0, 0, 0);
            saB[st] = __builtin_amdgcn_mfma_f32_16x16x32_bf16(kf1, qfB[1], saB[st], 0, 0, 0);
            if (doA) {
                saA[st] = __builtin_amdgcn_mfma_f32_16x16x32_bf16(kf0, qfA[0], zero4, 0, 0, 0);
                saA[st] = __builtin_amdgcn_mfma_f32_16x16x32_bf16(kf1, qfA[1], saA[st], 0, 0, 0);
            }
        }

        int kg0 = kt * 64 + quad * 4;
        short8 pfB0, pfB1, pfA0, pfA1;
        {
            float p[4][4];
#pragma unroll
            for (int st = 0; st < 4; st++)
#pragma unroll
                for (int r = 0; r < 4; r++)
                    p[st][r] = __builtin_amdgcn_exp2f(saB[st][r]);
            if (maskB) {
#pragma unroll
                for (int st = 0; st < 4; st++)
#pragma unroll
                    for (int r = 0; r < 4; r++)
                        if (kg0 + st * 16 + r > qrB) p[st][r] = 0.f;
            }
            float rs = 0.f;
#pragma unroll
            for (int st = 0; st < 4; st++) {
                rs += p[st][0] + p[st][1] + p[st][2] + p[st][3];
                uint2 pw;
                pw.x = pk2bf(p[st][0], p[st][1]);
                pw.y = pk2bf(p[st][2], p[st][3]);
                *(uint2*)&myP[pw_off + (((st * 2 + (quad >> 1)) ^ l7) * 8)] = pw;
            }
            rs += __shfl_xor(rs, 16, 64);
            rs += __shfl_xor(rs, 32, 64);
            lB += rs;
            pfB0 = ldsr(&myP[pr0]);
            pfB1 = ldsr(&myP[pr1]);
        }
        if (doA) {
            float p[4][4];
#pragma unroll
            for (int st = 0; st < 4; st++)
#pragma unroll
                for (int r = 0; r < 4; r++)
                    p[st][r] = __builtin_amdgcn_exp2f(saA[st][r]);
            if (maskA) {
#pragma unroll
                for (int st = 0; st < 4; st++)
#pragma unroll
                    for (int r = 0; r < 4; r++)
                        if (kg0 + st * 16 + r > qrA) p[st][r] = 0.f;
            }
            float rs = 0.f;
#pragma unroll
            for (int st = 0; st < 4; st++) {
                rs += p[st][0] + p[st][1] + p[st][2] + p[st][3];
                uint2 pw;
                pw.x = pk2bf(p[st][0], p[st][1]);
                pw.y = pk2bf(p[st][2], p[st][3]);
                *(uint2*)&myP[pw_off + (((st * 2 + (quad >> 1)) ^ l7) * 8)] = pw;
            }
            rs += __shfl_xor(rs, 16, 64);
            rs += __shfl_xor(rs, 32, 64);
            lA += rs;
            pfA0 = ldsr(&myP[pr0]);
            pfA1 = ldsr(&myP[pr1]);
        }

#pragma unroll
        for (int st = 0; st < 4; st++) {
            int row = st * 16 + l15;
            short8 vf0 = ldsr(&Vs[cur][row * 64 + ((quad ^ l7) * 8)]);
            short8 vf1 = ldsr(&Vs[cur][row * 64 + (((4 + quad) ^ l7) * 8)]);
            oB[st] = __builtin_amdgcn_mfma_f32_16x16x32_bf16(vf0, pfB0, oB[st], 0, 0, 0);
            oB[st] = __builtin_amdgcn_mfma_f32_16x16x32_bf16(vf1, pfB1, oB[st], 0, 0, 0);
            if (doA) {
                oA[st] = __builtin_amdgcn_mfma_f32_16x16x32_bf16(vf0, pfA0, oA[st], 0, 0, 0);
                oA[st] = __builtin_amdgcn_mfma_f32_16x16x32_bf16(vf1, pfA1, oA[st], 0, 0, 0);
            }
        }
        __syncthreads();
    }

    int b = bh >> 4, h = bh & 15;
    float invA = 1.f / lA, invB = 1.f / lB;
#pragma unroll
    for (int st = 0; st < 4; st++) {
        uint2 ov;
        ov.x = pk2bf(oA[st][0] * invA, oA[st][1] * invA);
        ov.y = pk2bf(oA[st][2] * invA, oA[st][3] * invA);
        *(uint2*)&O[((long)(b * 2048 + qrA)) * 1024 + h * 64 + st * 16 + quad * 4] = ov;
        uint2 ow;
        ow.x = pk2bf(oB[st][0] * invB, oB[st][1] * invB);
        ow.y = pk2bf(oB[st][2] * invB, oB[st][3] * invB);
        *(uint2*)&O[((long)(b * 2048 + qrB)) * 1024 + h * 64 + st * 16 + quad * 4] = ow;
    }
}

// ---------------- launch ----------------
extern "C" void kernel_launch(void* const* d_in, const int* in_sizes, int n_in,
                              void* d_out, int out_size, void* d_ws, size_t ws_size,
                              hipStream_t stream) {
    const float* x  = (const float*)d_in[0];
    const float* wq = (const float*)d_in[1];
    const float* bq = (const float*)d_in[2];
    const float* wk = (const float*)d_in[3];
    const float* bk = (const float*)d_in[4];
    const float* wv = (const float*)d_in[5];
    const float* bv = (const float*)d_in[6];
    const float* wo = (const float*)d_in[7];
    const float* bo = (const float*)d_in[8];

    char* w = (char*)d_ws;
    unsigned short* xb  = (unsigned short*)w;                    // 16MB
    unsigned short* wtq = (unsigned short*)(w + (16u << 20));    // wtq|wtk|wtv|wto contiguous
    unsigned short* wto = wtq + (3u << 20);
    unsigned short* qb  = wto + (1u << 20);
    unsigned short* kb  = qb + (8u << 20);
    unsigned short* vb  = kb + (8u << 20);                       // V^T [B,H,DK,S]
    unsigned short* ob  = vb + (8u << 20);

    prep_kernel<<<12288, 256, 0, stream>>>(x, xb, wq, wk, wv, wo, wtq);
    proj_kernel<<<dim3(8, 64), 512, 144 * 1024, stream>>>(xb, wtq, bq, bk, bv, qb, kb, vb);
    attn_kernel<<<1024, 256, 0, stream>>>(qb, kb, vb, ob);
    gemm_out_kernel<<<dim3(8, 32), 512, 144 * 1024, stream>>>(ob, wto, bo, (float*)d_out);
}